// Round 2
// baseline (1212.770 us; speedup 1.0000x reference)
//
#include <hip/hip_runtime.h>

#define FCn 64      // FC
#define LDP 68      // padded LDS row stride (floats)
#define TEB 64      // edges per block (pass 1)
#define GJK 576     // 9*64 floats of G per node
#define ABP 12      // padded A-row stride per node
#define ZBLK 512    // zero-fill blocks appended to precomp grid

__device__ __forceinline__ float silu_f(float x) { return x / (1.f + __expf(-x)); }

// ---------------- precompute: fold s, rad_w2/rad_b2, proj_w*, 0.25 into
// MT (224x64, transposed: MT[c][k]), cvec(224), b0s(128).
// Blocks >= 65 zero-fill G/Ab and cnt (replaces two hipMemsetAsync).
__global__ __launch_bounds__(256) void precomp_kernel(
    const float* __restrict__ exp_w, const float* __restrict__ exp_b,
    const float* __restrict__ rad_w2, const float* __restrict__ rad_b2,
    const float* __restrict__ proj_w0, const float* __restrict__ proj_b0,
    const float* __restrict__ proj_w1, const float* __restrict__ proj_w2,
    float* __restrict__ MT, float* __restrict__ cvec, float* __restrict__ b0s,
    float* __restrict__ zbase, long long zf4, int* __restrict__ cnt, int Nn)
{
    if (blockIdx.x >= 65) {
        const long long tid = (long long)(blockIdx.x - 65) * 256 + threadIdx.x;
        const long long stride = (long long)ZBLK * 256;
        float4 z = make_float4(0.f, 0.f, 0.f, 0.f);
        for (long long i = tid; i < zf4; i += stride) ((float4*)zbase)[i] = z;
        for (long long i = tid; i < Nn; i += stride) cnt[i] = 0;
        return;
    }
    const int r = blockIdx.x;   // 0..63 -> M row r; 64 -> cvec/b0s
    const int c = threadIdx.x;  // 0..255
    const float* wrow = (r < FCn) ? (rad_w2 + (long long)r * 384) : rad_b2;
    float acc = 0.f;
    if (c < 128) {
        for (int q = 0; q < 128; ++q)
            acc += wrow[q] * (exp_w[q] + exp_b[q]) * proj_w0[q * 128 + c];
    } else if (c < 192) {
        const int d = c - 128;
        for (int q = 0; q < 128; ++q)
            acc += wrow[128 + q] * (exp_w[q] + exp_b[q]) * proj_w1[q * 64 + d];
    } else if (c < 224) {
        const int d = c - 192;
        for (int q = 0; q < 128; ++q)
            acc += wrow[256 + q] * (exp_w[q] + exp_b[q]) * proj_w2[q * 32 + d];
    }
    acc *= 0.25f;  // 1/sqrt(AVG_AGG)
    if (r < FCn) {
        if (c < 224) MT[c * FCn + r] = acc;   // MT[c][k]
    } else {
        cvec[c] = acc;
        if (c < 128) b0s[c] = 0.25f * proj_b0[c];
    }
}

// ---------------- CSR build
__global__ __launch_bounds__(256) void hist_kernel(const int* __restrict__ dst, int* __restrict__ cnt, int E)
{
    for (int e = blockIdx.x * 256 + threadIdx.x; e < E; e += gridDim.x * 256)
        atomicAdd(&cnt[dst[e]], 1);
}

__global__ __launch_bounds__(256) void scan_kernel(const int* __restrict__ cnt, int* __restrict__ off,
                                                   int* __restrict__ cur, int Nn, int Etot)
{
    __shared__ int part[256];
    __shared__ int spart[257];
    const int t = threadIdx.x;
    const int per = (Nn + 255) / 256;
    int s = 0;
    #pragma unroll 8
    for (int i = 0; i < per; ++i) {
        const int idx = t * per + i;
        if (idx < Nn) s += cnt[idx];
    }
    part[t] = s;
    __syncthreads();
    if (t == 0) {
        int run = 0;
        spart[0] = 0;
        for (int i = 0; i < 256; ++i) { run += part[i]; spart[i + 1] = run; }
    }
    __syncthreads();
    int run = spart[t];
    #pragma unroll 8
    for (int i = 0; i < per; ++i) {
        const int idx = t * per + i;
        if (idx < Nn) { off[idx] = run; cur[idx] = run; run += cnt[idx]; }
    }
    if (t == 0) off[Nn] = Etot;
}

__global__ __launch_bounds__(256) void scatter_kernel(const int* __restrict__ dst, int* __restrict__ cur,
                                                      int* __restrict__ eids, int E)
{
    for (int e = blockIdx.x * 256 + threadIdx.x; e < E; e += gridDim.x * 256) {
        const int pos = atomicAdd(&cur[dst[e]], 1);
        eids[pos] = e;
    }
}

// ---------------- pass 1: GEMM1 + in-register LN/silu + segment-accumulate G
__global__ __launch_bounds__(256, 7) void accumG_kernel(
    const float* __restrict__ edge_attr,    // E x 9
    const float* __restrict__ edge_scalars, // E x 64
    const int*   __restrict__ eids,         // E (sorted pos -> edge id)
    const int*   __restrict__ edge_dst,     // E
    const float* __restrict__ rad_w1,       // 64 x 64
    const float* __restrict__ rad_b1,       // 64
    const float* __restrict__ rad_gamma,    // 64
    const float* __restrict__ rad_beta,     // 64
    float* __restrict__ G,                  // N x 576 (zero-initialized)
    float* __restrict__ Ab,                 // N x 12  (zero-initialized)
    int E)
{
    __shared__ float XT[FCn * LDP];   // X^T [k][e]; reused as He [e][k] after LN
    __shared__ float Ea[TEB * ABP];   // [e][j]
    __shared__ int   dst_l[TEB];
    const int t = threadIdx.x;
    const int p0 = blockIdx.x * TEB;

    if (t < TEB) {
        const int p = p0 + t;
        const int eid = (p < E) ? eids[p] : -1;
        dst_l[t] = (eid >= 0) ? edge_dst[eid] : -1;
    }

    // ---- stage X^T (gathered 256B rows) + edge_attr (eids read via L1 broadcast)
    #pragma unroll
    for (int i = 0; i < 4; ++i) {
        const int idx = i * 256 + t;
        const int e  = idx >> 4;
        const int kq = idx & 15;
        const int p  = p0 + e;
        const int eid = (p < E) ? eids[p] : -1;
        float4 v = make_float4(0.f, 0.f, 0.f, 0.f);
        if (eid >= 0) v = *(const float4*)(edge_scalars + (long long)eid * FCn + kq * 4);
        XT[(kq * 4 + 0) * LDP + e] = v.x;
        XT[(kq * 4 + 1) * LDP + e] = v.y;
        XT[(kq * 4 + 2) * LDP + e] = v.z;
        XT[(kq * 4 + 3) * LDP + e] = v.w;
    }
    for (int i = t; i < TEB * 9; i += 256) {
        const int e = i / 9, j = i - e * 9;
        const int p = p0 + e;
        const int eid = (p < E) ? eids[p] : -1;
        Ea[e * ABP + j] = (eid >= 0) ? edge_attr[(long long)eid * 9 + j] : 0.f;
    }
    __syncthreads();

    // ---- GEMM1: H = X @ W1 + b1 (64e x 64c), per-thread 4x4, acc in regs
    const int eg = t >> 4, cg = t & 15;
    float a[4][4];
    #pragma unroll
    for (int i = 0; i < 4; ++i)
        #pragma unroll
        for (int j = 0; j < 4; ++j) a[i][j] = 0.f;
    for (int k = 0; k < FCn; ++k) {
        const float4 xv = *(const float4*)&XT[k * LDP + eg * 4];
        const float4 wv = *(const float4*)&rad_w1[k * FCn + cg * 4];
        const float xe[4] = {xv.x, xv.y, xv.z, xv.w};
        const float wc[4] = {wv.x, wv.y, wv.z, wv.w};
        #pragma unroll
        for (int i = 0; i < 4; ++i)
            #pragma unroll
            for (int j = 0; j < 4; ++j)
                a[i][j] += xe[i] * wc[j];
    }
    {
        const float4 bv = *(const float4*)&rad_b1[cg * 4];
        const float bb[4] = {bv.x, bv.y, bv.z, bv.w};
        #pragma unroll
        for (int i = 0; i < 4; ++i)
            #pragma unroll
            for (int j = 0; j < 4; ++j) a[i][j] += bb[j];
    }

    // ---- LN stats: reduce across the 16 cg-lanes (contiguous in wave)
    float s1[4], s2[4];
    #pragma unroll
    for (int i = 0; i < 4; ++i) {
        s1[i] = a[i][0] + a[i][1] + a[i][2] + a[i][3];
        s2[i] = a[i][0]*a[i][0] + a[i][1]*a[i][1] + a[i][2]*a[i][2] + a[i][3]*a[i][3];
    }
    #pragma unroll
    for (int m = 1; m < 16; m <<= 1) {
        #pragma unroll
        for (int i = 0; i < 4; ++i) {
            s1[i] += __shfl_xor(s1[i], m);
            s2[i] += __shfl_xor(s2[i], m);
        }
    }

    __syncthreads();   // all XT (X^T) reads done; safe to overwrite with He

    {
        const float4 gm = *(const float4*)&rad_gamma[cg * 4];
        const float4 bt = *(const float4*)&rad_beta[cg * 4];
        const float gv[4] = {gm.x, gm.y, gm.z, gm.w};
        const float bv2[4] = {bt.x, bt.y, bt.z, bt.w};
        #pragma unroll
        for (int i = 0; i < 4; ++i) {
            const float mu  = s1[i] * (1.f / 64.f);
            const float var = s2[i] * (1.f / 64.f) - mu * mu;
            const float rs  = rsqrtf(var + 1e-5f);
            float o[4];
            #pragma unroll
            for (int j = 0; j < 4; ++j) {
                const float x = (a[i][j] - mu) * rs * gv[j] + bv2[j];
                o[j] = silu_f(x);
            }
            *(float4*)&XT[(eg * 4 + i) * LDP + cg * 4] = make_float4(o[0], o[1], o[2], o[3]);
        }
    }
    __syncthreads();

    // ---- segment accumulation of G and A (registers), flush on dst change.
    // dst_l is non-decreasing (CSR order) -> wave-uniform 4-edge fast path.
    const int k  = t & 63;
    const int jg = t >> 6;            // 0..3
    const int j0 = jg, j1 = jg + 4;   // jg==0 additionally owns j=8
    const bool has2 = (jg == 0);
    float g0 = 0.f, g1 = 0.f, g2 = 0.f;
    float a0 = 0.f, a1 = 0.f, a2 = 0.f;
    int curn = dst_l[0];
    int e = 0;
    while (e < TEB) {
        const int nid = dst_l[e];
        if (nid != curn) {
            if (curn >= 0) {
                float* gp = G + (long long)curn * GJK;
                atomicAdd(gp + j0 * 64 + k, g0);
                atomicAdd(gp + j1 * 64 + k, g1);
                if (has2) atomicAdd(gp + 8 * 64 + k, g2);
                if (k == 0) {
                    float* ap = Ab + (long long)curn * ABP;
                    atomicAdd(ap + j0, a0);
                    atomicAdd(ap + j1, a1);
                    if (has2) atomicAdd(ap + 8, a2);
                }
            }
            g0 = g1 = g2 = 0.f; a0 = a1 = a2 = 0.f;
            curn = nid;
        }
        if (nid < 0) break;
        if (e + 4 <= TEB && dst_l[e + 3] == nid) {
            #pragma unroll
            for (int u = 0; u < 4; ++u) {
                const int eu = e + u;
                const float h  = XT[eu * LDP + k];
                const float e0 = Ea[eu * ABP + j0];
                const float e1 = Ea[eu * ABP + j1];
                g0 = fmaf(e0, h, g0); a0 += e0;
                g1 = fmaf(e1, h, g1); a1 += e1;
                if (has2) {
                    const float e2 = Ea[eu * ABP + 8];
                    g2 = fmaf(e2, h, g2); a2 += e2;
                }
            }
            e += 4;
        } else {
            const float h  = XT[e * LDP + k];
            const float e0 = Ea[e * ABP + j0];
            const float e1 = Ea[e * ABP + j1];
            g0 = fmaf(e0, h, g0); a0 += e0;
            g1 = fmaf(e1, h, g1); a1 += e1;
            if (has2) {
                const float e2 = Ea[e * ABP + 8];
                g2 = fmaf(e2, h, g2); a2 += e2;
            }
            e += 1;
        }
    }
    if (curn >= 0) {
        float* gp = G + (long long)curn * GJK;
        atomicAdd(gp + j0 * 64 + k, g0);
        atomicAdd(gp + j1 * 64 + k, g1);
        if (has2) atomicAdd(gp + 8 * 64 + k, g2);
        if (k == 0) {
            float* ap = Ab + (long long)curn * ABP;
            atomicAdd(ap + j0, a0);
            atomicAdd(ap + j1, a1);
            if (has2) atomicAdd(ap + 8, a2);
        }
    }
}

// ---------------- pass 2: out[n,c] = G[n,j(c),:]·MT[t(c),:] + Ab[n,j(c)]*cvec[t(c)]
//                                     + (c<128 ? deg*b0s[c] : 0)
// MT row held in registers per thread; 8 nodes/iteration; Gs reads broadcast.
__global__ __launch_bounds__(512, 4) void project_kernel(
    const float* __restrict__ G, const float* __restrict__ Ab,
    const int*   __restrict__ off,
    const float* __restrict__ MT, const float* __restrict__ cvec,
    const float* __restrict__ b0s,
    float* __restrict__ out, int Nn)
{
    __shared__ float Gs[8 * GJK];     // 18432 B
    __shared__ float sA[8 * ABP];
    __shared__ int   dg[8];
    const int t = threadIdx.x;

    // out col t -> (T col, edge_attr col)
    int tIdx = 0, jIdx = 0;
    if (t < 128)      { tIdx = t; jIdx = 0; }
    else if (t < 320) { const int idx = t - 128; tIdx = 128 + idx / 3; jIdx = 1 + idx % 3; }
    else if (t < 480) { const int idx = t - 320; tIdx = 192 + idx / 5; jIdx = 4 + idx % 5; }

    // MT row into registers (64 floats), constants from global (L2-resident)
    float4 m[16];
    {
        const float* mrow = MT + tIdx * FCn;
        #pragma unroll
        for (int q = 0; q < 16; ++q) m[q] = *(const float4*)(mrow + q * 4);
    }
    const float cvv = cvec[tIdx];
    const float bsv = (t < 128) ? b0s[t] : 0.f;

    for (int n0 = blockIdx.x * 8; n0 < Nn; n0 += gridDim.x * 8) {
        const int nvalid = min(8, Nn - n0);
        const int nf4 = (nvalid * GJK) >> 2;
        for (int i = t; i < nf4; i += 512)
            ((float4*)Gs)[i] = *(const float4*)(G + (long long)n0 * GJK + i * 4);
        if (t < 8 * ABP) {
            const int nb = t / ABP, j = t - nb * ABP;
            const int n = n0 + nb;
            sA[t] = (n < Nn) ? Ab[(long long)n * ABP + j] : 0.f;
        }
        if (t < 8) {
            const int n = n0 + t;
            dg[t] = (n < Nn) ? off[n + 1] - off[n] : 0;
        }
        __syncthreads();

        float acc[8];
        #pragma unroll
        for (int nb = 0; nb < 8; ++nb)
            acc[nb] = sA[nb * ABP + jIdx] * cvv + (float)dg[nb] * bsv;
        const float* gbase = Gs + jIdx * 64;
        #pragma unroll
        for (int q = 0; q < 16; ++q) {
            const float4 mq = m[q];
            #pragma unroll
            for (int nb = 0; nb < 8; ++nb) {
                const float4 g = *(const float4*)(gbase + nb * GJK + q * 4);
                acc[nb] += mq.x * g.x + mq.y * g.y + mq.z * g.z + mq.w * g.w;
            }
        }
        if (t < 480) {
            #pragma unroll
            for (int nb = 0; nb < 8; ++nb) {
                if (n0 + nb < Nn)
                    out[(long long)(n0 + nb) * 480 + t] = acc[nb];
            }
        }
        __syncthreads();
    }
}

extern "C" void kernel_launch(void* const* d_in, const int* in_sizes, int n_in,
                              void* d_out, int out_size, void* d_ws, size_t ws_size,
                              hipStream_t stream)
{
    const float* edge_attr    = (const float*)d_in[1];
    const float* edge_scalars = (const float*)d_in[2];
    const int*   edge_dst     = (const int*)d_in[4];
    const float* exp_w     = (const float*)d_in[6];
    const float* exp_b     = (const float*)d_in[7];
    const float* rad_w1    = (const float*)d_in[8];
    const float* rad_b1    = (const float*)d_in[9];
    const float* rad_gamma = (const float*)d_in[10];
    const float* rad_beta  = (const float*)d_in[11];
    const float* rad_w2    = (const float*)d_in[12];
    const float* rad_b2    = (const float*)d_in[13];
    const float* proj_w0   = (const float*)d_in[14];
    const float* proj_b0   = (const float*)d_in[15];
    const float* proj_w1   = (const float*)d_in[16];
    const float* proj_w2   = (const float*)d_in[17];
    float* out = (float*)d_out;
    const int E = in_sizes[4];
    const int Nn = out_size / 480;

    // ws layout: MT, cvec, b0s, off, cnt, cur, eids, G, Ab
    float* MT   = (float*)d_ws;                 // 224*64
    float* cvec = MT + 224 * FCn;               // 256
    float* b0s  = cvec + 256;                   // 128
    int* off  = (int*)(b0s + 128);              // Nn+1
    int* cnt  = off + (Nn + 1);                 // Nn
    int* cur  = cnt + Nn;                       // Nn
    int* eids = cur + Nn;                       // E
    size_t gOff = (size_t)((char*)(eids + E) - (char*)d_ws);
    gOff = (gOff + 255) & ~(size_t)255;
    float* G  = (float*)((char*)d_ws + gOff);   // Nn x 576
    float* Ab = G + (size_t)Nn * GJK;           // Nn x 12 (contiguous with G)

    const long long zf4 = ((long long)Nn * (GJK + ABP)) >> 2;  // G+Ab float4 count
    precomp_kernel<<<65 + ZBLK, 256, 0, stream>>>(exp_w, exp_b, rad_w2, rad_b2,
                                                  proj_w0, proj_b0, proj_w1, proj_w2,
                                                  MT, cvec, b0s, G, zf4, cnt, Nn);
    hist_kernel<<<512, 256, 0, stream>>>(edge_dst, cnt, E);
    scan_kernel<<<1, 256, 0, stream>>>(cnt, off, cur, Nn, E);
    scatter_kernel<<<512, 256, 0, stream>>>(edge_dst, cur, eids, E);

    const int blocks = (E + TEB - 1) / TEB;
    accumG_kernel<<<blocks, 256, 0, stream>>>(edge_attr, edge_scalars, eids, edge_dst,
                                              rad_w1, rad_b1, rad_gamma, rad_beta,
                                              G, Ab, E);
    project_kernel<<<512, 512, 0, stream>>>(G, Ab, off, MT, cvec, b0s, out, Nn);
}

// Round 4
// 923.533 us; speedup vs baseline: 1.3132x; 1.3132x over previous
//
#include <hip/hip_runtime.h>

#define FCn 64      // FC
#define LDP 68      // padded LDS row stride (floats)
#define TEB 64      // edges per block (pass 1)
#define GJK 576     // 9*64 floats of G per node
#define GJS 612     // 9*68 padded LDS stride per node (project)
#define ABP 12      // padded A-row stride per node
#define ZBLK 512    // zero-fill blocks appended to precomp grid

__device__ __forceinline__ float silu_f(float x) { return x / (1.f + __expf(-x)); }

// ---------------- precompute: fold s, rad_w2/rad_b2, proj_w*, 0.25 into
// MT (224x64, transposed: MT[c][k]), cvec(224), b0s(128).
// Blocks >= 65 zero-fill G/Ab and cnt (replaces two hipMemsetAsync).
__global__ __launch_bounds__(256) void precomp_kernel(
    const float* __restrict__ exp_w, const float* __restrict__ exp_b,
    const float* __restrict__ rad_w2, const float* __restrict__ rad_b2,
    const float* __restrict__ proj_w0, const float* __restrict__ proj_b0,
    const float* __restrict__ proj_w1, const float* __restrict__ proj_w2,
    float* __restrict__ MT, float* __restrict__ cvec, float* __restrict__ b0s,
    float* __restrict__ zbase, long long zf4, int* __restrict__ cnt, int Nn)
{
    if (blockIdx.x >= 65) {
        const long long tid = (long long)(blockIdx.x - 65) * 256 + threadIdx.x;
        const long long stride = (long long)ZBLK * 256;
        float4 z = make_float4(0.f, 0.f, 0.f, 0.f);
        for (long long i = tid; i < zf4; i += stride) ((float4*)zbase)[i] = z;
        for (long long i = tid; i < Nn; i += stride) cnt[i] = 0;
        return;
    }
    const int r = blockIdx.x;   // 0..63 -> M row r; 64 -> cvec/b0s
    const int c = threadIdx.x;  // 0..255
    const float* wrow = (r < FCn) ? (rad_w2 + (long long)r * 384) : rad_b2;
    float acc = 0.f;
    if (c < 128) {
        for (int q = 0; q < 128; ++q)
            acc += wrow[q] * (exp_w[q] + exp_b[q]) * proj_w0[q * 128 + c];
    } else if (c < 192) {
        const int d = c - 128;
        for (int q = 0; q < 128; ++q)
            acc += wrow[128 + q] * (exp_w[q] + exp_b[q]) * proj_w1[q * 64 + d];
    } else if (c < 224) {
        const int d = c - 192;
        for (int q = 0; q < 128; ++q)
            acc += wrow[256 + q] * (exp_w[q] + exp_b[q]) * proj_w2[q * 32 + d];
    }
    acc *= 0.25f;  // 1/sqrt(AVG_AGG)
    if (r < FCn) {
        if (c < 224) MT[c * FCn + r] = acc;   // MT[c][k]
    } else {
        cvec[c] = acc;
        if (c < 128) b0s[c] = 0.25f * proj_b0[c];
    }
}

// ---------------- CSR build
__global__ __launch_bounds__(256) void hist_kernel(const int* __restrict__ dst, int* __restrict__ cnt, int E)
{
    for (int e = blockIdx.x * 256 + threadIdx.x; e < E; e += gridDim.x * 256)
        atomicAdd(&cnt[dst[e]], 1);
}

__global__ __launch_bounds__(256) void scan_kernel(const int* __restrict__ cnt, int* __restrict__ off,
                                                   int* __restrict__ cur, int Nn, int Etot)
{
    __shared__ int part[256];
    __shared__ int spart[257];
    const int t = threadIdx.x;
    const int per = (Nn + 255) / 256;
    int s = 0;
    #pragma unroll 8
    for (int i = 0; i < per; ++i) {
        const int idx = t * per + i;
        if (idx < Nn) s += cnt[idx];
    }
    part[t] = s;
    __syncthreads();
    if (t == 0) {
        int run = 0;
        spart[0] = 0;
        for (int i = 0; i < 256; ++i) { run += part[i]; spart[i + 1] = run; }
    }
    __syncthreads();
    int run = spart[t];
    #pragma unroll 8
    for (int i = 0; i < per; ++i) {
        const int idx = t * per + i;
        if (idx < Nn) { off[idx] = run; cur[idx] = run; run += cnt[idx]; }
    }
    if (t == 0) off[Nn] = Etot;
}

__global__ __launch_bounds__(256) void scatter_kernel(const int* __restrict__ dst, int* __restrict__ cur,
                                                      int* __restrict__ eids, int E)
{
    for (int e = blockIdx.x * 256 + threadIdx.x; e < E; e += gridDim.x * 256) {
        const int pos = atomicAdd(&cur[dst[e]], 1);
        eids[pos] = e;
    }
}

// ---------------- pass 1: GEMM1 + in-register LN/silu + segment-accumulate G
__global__ __launch_bounds__(256, 7) void accumG_kernel(
    const float* __restrict__ edge_attr,    // E x 9
    const float* __restrict__ edge_scalars, // E x 64
    const int*   __restrict__ eids,         // E (sorted pos -> edge id)
    const int*   __restrict__ edge_dst,     // E
    const float* __restrict__ rad_w1,       // 64 x 64
    const float* __restrict__ rad_b1,       // 64
    const float* __restrict__ rad_gamma,    // 64
    const float* __restrict__ rad_beta,     // 64
    float* __restrict__ G,                  // N x 576 (zero-initialized)
    float* __restrict__ Ab,                 // N x 12  (zero-initialized)
    int E)
{
    __shared__ float XT[FCn * LDP];   // X^T [k][e]; reused as He [e][k] after LN
    __shared__ float Ea[TEB * ABP];   // [e][j]
    __shared__ int   dst_l[TEB];
    const int t = threadIdx.x;
    const int p0 = blockIdx.x * TEB;

    if (t < TEB) {
        const int p = p0 + t;
        const int eid = (p < E) ? eids[p] : -1;
        dst_l[t] = (eid >= 0) ? edge_dst[eid] : -1;
    }

    // ---- stage X^T (gathered 256B rows) + edge_attr (eids read via L1 broadcast)
    #pragma unroll
    for (int i = 0; i < 4; ++i) {
        const int idx = i * 256 + t;
        const int e  = idx >> 4;
        const int kq = idx & 15;
        const int p  = p0 + e;
        const int eid = (p < E) ? eids[p] : -1;
        float4 v = make_float4(0.f, 0.f, 0.f, 0.f);
        if (eid >= 0) v = *(const float4*)(edge_scalars + (long long)eid * FCn + kq * 4);
        XT[(kq * 4 + 0) * LDP + e] = v.x;
        XT[(kq * 4 + 1) * LDP + e] = v.y;
        XT[(kq * 4 + 2) * LDP + e] = v.z;
        XT[(kq * 4 + 3) * LDP + e] = v.w;
    }
    for (int i = t; i < TEB * 9; i += 256) {
        const int e = i / 9, j = i - e * 9;
        const int p = p0 + e;
        const int eid = (p < E) ? eids[p] : -1;
        Ea[e * ABP + j] = (eid >= 0) ? edge_attr[(long long)eid * 9 + j] : 0.f;
    }
    __syncthreads();

    // ---- GEMM1: H = X @ W1 + b1 (64e x 64c), per-thread 4x4, acc in regs
    const int eg = t >> 4, cg = t & 15;
    float a[4][4];
    #pragma unroll
    for (int i = 0; i < 4; ++i)
        #pragma unroll
        for (int j = 0; j < 4; ++j) a[i][j] = 0.f;
    for (int k = 0; k < FCn; ++k) {
        const float4 xv = *(const float4*)&XT[k * LDP + eg * 4];
        const float4 wv = *(const float4*)&rad_w1[k * FCn + cg * 4];
        const float xe[4] = {xv.x, xv.y, xv.z, xv.w};
        const float wc[4] = {wv.x, wv.y, wv.z, wv.w};
        #pragma unroll
        for (int i = 0; i < 4; ++i)
            #pragma unroll
            for (int j = 0; j < 4; ++j)
                a[i][j] += xe[i] * wc[j];
    }
    {
        const float4 bv = *(const float4*)&rad_b1[cg * 4];
        const float bb[4] = {bv.x, bv.y, bv.z, bv.w};
        #pragma unroll
        for (int i = 0; i < 4; ++i)
            #pragma unroll
            for (int j = 0; j < 4; ++j) a[i][j] += bb[j];
    }

    // ---- LN stats: reduce across the 16 cg-lanes (contiguous in wave)
    float s1[4], s2[4];
    #pragma unroll
    for (int i = 0; i < 4; ++i) {
        s1[i] = a[i][0] + a[i][1] + a[i][2] + a[i][3];
        s2[i] = a[i][0]*a[i][0] + a[i][1]*a[i][1] + a[i][2]*a[i][2] + a[i][3]*a[i][3];
    }
    #pragma unroll
    for (int m = 1; m < 16; m <<= 1) {
        #pragma unroll
        for (int i = 0; i < 4; ++i) {
            s1[i] += __shfl_xor(s1[i], m);
            s2[i] += __shfl_xor(s2[i], m);
        }
    }

    __syncthreads();   // all XT (X^T) reads done; safe to overwrite with He

    {
        const float4 gm = *(const float4*)&rad_gamma[cg * 4];
        const float4 bt = *(const float4*)&rad_beta[cg * 4];
        const float gv[4] = {gm.x, gm.y, gm.z, gm.w};
        const float bv2[4] = {bt.x, bt.y, bt.z, bt.w};
        #pragma unroll
        for (int i = 0; i < 4; ++i) {
            const float mu  = s1[i] * (1.f / 64.f);
            const float var = s2[i] * (1.f / 64.f) - mu * mu;
            const float rs  = rsqrtf(var + 1e-5f);
            float o[4];
            #pragma unroll
            for (int j = 0; j < 4; ++j) {
                const float x = (a[i][j] - mu) * rs * gv[j] + bv2[j];
                o[j] = silu_f(x);
            }
            *(float4*)&XT[(eg * 4 + i) * LDP + cg * 4] = make_float4(o[0], o[1], o[2], o[3]);
        }
    }
    __syncthreads();

    // ---- segment accumulation of G and A (registers), flush on dst change.
    // dst_l is non-decreasing (CSR order) -> wave-uniform 4-edge fast path.
    const int k  = t & 63;
    const int jg = t >> 6;            // 0..3
    const int j0 = jg, j1 = jg + 4;   // jg==0 additionally owns j=8
    const bool has2 = (jg == 0);
    float g0 = 0.f, g1 = 0.f, g2 = 0.f;
    float a0 = 0.f, a1 = 0.f, a2 = 0.f;
    int curn = dst_l[0];
    int e = 0;
    while (e < TEB) {
        const int nid = dst_l[e];
        if (nid != curn) {
            if (curn >= 0) {
                float* gp = G + (long long)curn * GJK;
                atomicAdd(gp + j0 * 64 + k, g0);
                atomicAdd(gp + j1 * 64 + k, g1);
                if (has2) atomicAdd(gp + 8 * 64 + k, g2);
                if (k == 0) {
                    float* ap = Ab + (long long)curn * ABP;
                    atomicAdd(ap + j0, a0);
                    atomicAdd(ap + j1, a1);
                    if (has2) atomicAdd(ap + 8, a2);
                }
            }
            g0 = g1 = g2 = 0.f; a0 = a1 = a2 = 0.f;
            curn = nid;
        }
        if (nid < 0) break;
        if (e + 4 <= TEB && dst_l[e + 3] == nid) {
            #pragma unroll
            for (int u = 0; u < 4; ++u) {
                const int eu = e + u;
                const float h  = XT[eu * LDP + k];
                const float e0 = Ea[eu * ABP + j0];
                const float e1 = Ea[eu * ABP + j1];
                g0 = fmaf(e0, h, g0); a0 += e0;
                g1 = fmaf(e1, h, g1); a1 += e1;
                if (has2) {
                    const float e2 = Ea[eu * ABP + 8];
                    g2 = fmaf(e2, h, g2); a2 += e2;
                }
            }
            e += 4;
        } else {
            const float h  = XT[e * LDP + k];
            const float e0 = Ea[e * ABP + j0];
            const float e1 = Ea[e * ABP + j1];
            g0 = fmaf(e0, h, g0); a0 += e0;
            g1 = fmaf(e1, h, g1); a1 += e1;
            if (has2) {
                const float e2 = Ea[e * ABP + 8];
                g2 = fmaf(e2, h, g2); a2 += e2;
            }
            e += 1;
        }
    }
    if (curn >= 0) {
        float* gp = G + (long long)curn * GJK;
        atomicAdd(gp + j0 * 64 + k, g0);
        atomicAdd(gp + j1 * 64 + k, g1);
        if (has2) atomicAdd(gp + 8 * 64 + k, g2);
        if (k == 0) {
            float* ap = Ab + (long long)curn * ABP;
            atomicAdd(ap + j0, a0);
            atomicAdd(ap + j1, a1);
            if (has2) atomicAdd(ap + 8, a2);
        }
    }
}

// ---------------- pass 2: out[n,c] = G[n,j(c),:]·MT[t(c),:] + Ab[n,j(c)]*cvec[t(c)]
//                                     + (c<128 ? deg*b0s[c] : 0)
// MT row held in registers per thread (NO min-waves bound: the round-2
// __launch_bounds__(512,4) capped VGPRs at 64 and spilled the 64-float MT
// row to scratch -> 2.8 GB of scratch traffic). 8 nodes/iteration.
// Gs padded to 68-float j-stride: j-groups hit disjoint bank quads.
__global__ __launch_bounds__(512) void project_kernel(
    const float* __restrict__ G, const float* __restrict__ Ab,
    const int*   __restrict__ off,
    const float* __restrict__ MT, const float* __restrict__ cvec,
    const float* __restrict__ b0s,
    float* __restrict__ out, int Nn)
{
    __shared__ float Gs[8 * GJS];     // 19584 B, [nb][j][68]
    __shared__ float sA[8 * ABP];
    __shared__ int   dg[8];
    const int t = threadIdx.x;

    // out col t -> (T col, edge_attr col)
    int tIdx = 0, jIdx = 0;
    if (t < 128)      { tIdx = t; jIdx = 0; }
    else if (t < 320) { const int idx = t - 128; tIdx = 128 + idx / 3; jIdx = 1 + idx % 3; }
    else if (t < 480) { const int idx = t - 320; tIdx = 192 + idx / 5; jIdx = 4 + idx % 5; }

    // MT row into registers (64 floats), constants from global (L2-resident)
    float4 m[16];
    {
        const float* mrow = MT + tIdx * FCn;
        #pragma unroll
        for (int q = 0; q < 16; ++q) m[q] = *(const float4*)(mrow + q * 4);
    }
    const float cvv = cvec[tIdx];
    const float bsv = (t < 128) ? b0s[t] : 0.f;

    for (int n0 = blockIdx.x * 8; n0 < Nn; n0 += gridDim.x * 8) {
        const int nvalid = min(8, Nn - n0);
        const int nf4 = nvalid * (GJK >> 2);     // 144 float4 per node
        for (int i = t; i < nf4; i += 512) {
            const int nb = i / 144;
            const int rem = i - nb * 144;
            const int j  = rem >> 4;
            const int kq = rem & 15;
            const float4 v = *(const float4*)(G + (long long)n0 * GJK + i * 4);
            *(float4*)(Gs + nb * GJS + j * 68 + kq * 4) = v;
        }
        if (t < 8 * ABP) {
            const int nb = t / ABP, j = t - nb * ABP;
            const int n = n0 + nb;
            sA[t] = (n < Nn) ? Ab[(long long)n * ABP + j] : 0.f;
        }
        if (t < 8) {
            const int n = n0 + t;
            dg[t] = (n < Nn) ? off[n + 1] - off[n] : 0;
        }
        __syncthreads();

        float acc[8];
        #pragma unroll
        for (int nb = 0; nb < 8; ++nb)
            acc[nb] = sA[nb * ABP + jIdx] * cvv + (float)dg[nb] * bsv;
        const float* gbase = Gs + jIdx * 68;
        #pragma unroll
        for (int q = 0; q < 16; ++q) {
            const float4 mq = m[q];
            #pragma unroll
            for (int nb = 0; nb < 8; ++nb) {
                const float4 g = *(const float4*)(gbase + nb * GJS + q * 4);
                acc[nb] += mq.x * g.x + mq.y * g.y + mq.z * g.z + mq.w * g.w;
            }
        }
        if (t < 480) {
            #pragma unroll
            for (int nb = 0; nb < 8; ++nb) {
                if (n0 + nb < Nn)
                    out[(long long)(n0 + nb) * 480 + t] = acc[nb];
            }
        }
        __syncthreads();
    }
}

extern "C" void kernel_launch(void* const* d_in, const int* in_sizes, int n_in,
                              void* d_out, int out_size, void* d_ws, size_t ws_size,
                              hipStream_t stream)
{
    const float* edge_attr    = (const float*)d_in[1];
    const float* edge_scalars = (const float*)d_in[2];
    const int*   edge_dst     = (const int*)d_in[4];
    const float* exp_w     = (const float*)d_in[6];
    const float* exp_b     = (const float*)d_in[7];
    const float* rad_w1    = (const float*)d_in[8];
    const float* rad_b1    = (const float*)d_in[9];
    const float* rad_gamma = (const float*)d_in[10];
    const float* rad_beta  = (const float*)d_in[11];
    const float* rad_w2    = (const float*)d_in[12];
    const float* rad_b2    = (const float*)d_in[13];
    const float* proj_w0   = (const float*)d_in[14];
    const float* proj_b0   = (const float*)d_in[15];
    const float* proj_w1   = (const float*)d_in[16];
    const float* proj_w2   = (const float*)d_in[17];
    float* out = (float*)d_out;
    const int E = in_sizes[4];
    const int Nn = out_size / 480;

    // ws layout: MT, cvec, b0s, off, cnt, cur, eids, G, Ab
    float* MT   = (float*)d_ws;                 // 224*64
    float* cvec = MT + 224 * FCn;               // 256
    float* b0s  = cvec + 256;                   // 128
    int* off  = (int*)(b0s + 128);              // Nn+1
    int* cnt  = off + (Nn + 1);                 // Nn
    int* cur  = cnt + Nn;                       // Nn
    int* eids = cur + Nn;                       // E
    size_t gOff = (size_t)((char*)(eids + E) - (char*)d_ws);
    gOff = (gOff + 255) & ~(size_t)255;
    float* G  = (float*)((char*)d_ws + gOff);   // Nn x 576
    float* Ab = G + (size_t)Nn * GJK;           // Nn x 12 (contiguous with G)

    const long long zf4 = ((long long)Nn * (GJK + ABP)) >> 2;  // G+Ab float4 count
    precomp_kernel<<<65 + ZBLK, 256, 0, stream>>>(exp_w, exp_b, rad_w2, rad_b2,
                                                  proj_w0, proj_b0, proj_w1, proj_w2,
                                                  MT, cvec, b0s, G, zf4, cnt, Nn);
    hist_kernel<<<512, 256, 0, stream>>>(edge_dst, cnt, E);
    scan_kernel<<<1, 256, 0, stream>>>(cnt, off, cur, Nn, E);
    scatter_kernel<<<512, 256, 0, stream>>>(edge_dst, cur, eids, E);

    const int blocks = (E + TEB - 1) / TEB;
    accumG_kernel<<<blocks, 256, 0, stream>>>(edge_attr, edge_scalars, eids, edge_dst,
                                              rad_w1, rad_b1, rad_gamma, rad_beta,
                                              G, Ab, E);
    project_kernel<<<1024, 512, 0, stream>>>(G, Ab, off, MT, cvec, b0s, out, Nn);
}